// Round 6
// baseline (199.837 us; speedup 1.0000x reference)
//
#include <hip/hip_runtime.h>

// ImplicitFunction MLP via fp16 MFMA, round 6: persistent register-resident
// weights, zero LDS, TWO waves per SIMD (round 5 ran 1 wave/SIMD -> all
// MFMA latency + VALU dependency stalls exposed; occupancy 10%).
//
// Changes vs round 5:
//  - grid 2048 one-wave blocks, __launch_bounds__(64,2): 2 waves/SIMD so one
//    wave's MFMA overlaps the other's pack-VALU (m114 co-scheduling).
//  - bias state compressed 52 -> ~14 VGPRs: all 6 hidden-layer biases packed
//    into k-slots of two A-frags (biasAll[t], A[m][k=l] = b_l[m]/64);
//    bc_l = mfma(biasAll, e_l, 0) with e_l a constant one-hot-k B-frag.
//    Frees headroom so the 2-wave VGPR cap (256) doesn't force spills.
//
// Math (unchanged): activations scaled 1/64 (lrelu positively homogeneous);
// K-permuted weights make the layer transition exchange-free; lrelu packed
// fp16. Layer-0 bias rides the unused k=3 slot of W0 (B gets 1.0).
// Layouts (gfx950, 32x32x16):
//   A/B frag: lane (i=lane&31, h=lane>>5) holds k = 8h+j, j=0..7
//   C/D:      col n = lane&31, row m = (r&3) + 8*(r>>2) + 4h, r=0..15

typedef _Float16 half8 __attribute__((ext_vector_type(8)));
typedef _Float16 half2v __attribute__((ext_vector_type(2)));
typedef float floatx16 __attribute__((ext_vector_type(16)));
typedef float float2v __attribute__((ext_vector_type(2)));

#define N_HID 6
// ws byte offsets
#define OFF_A 0        // hidden W frags [l:6][t:2][s:4][lane:64][j:8] fp16 = 49152
#define OFF_B 49152    // layer0 A frags [t:2][lane:64][j:8] fp16 (bias@k=3) = 2048
#define OFF_E 51200    // biasAll frags  [t:2][lane:64][j:8] fp16 (k-slot=l) = 2048
#define OFF_D 53248    // wo*so*64 fp32, C-layout [h:2][t:2][r:16]          = 256
#define SETUP_TOTAL (24576 + 1024 + 1024 + 64)

__global__ __launch_bounds__(256) void setup_weights(
    const float* __restrict__ w0, const float* __restrict__ s0, const float* __restrict__ b0,
    const float* __restrict__ wh, const float* __restrict__ sh, const float* __restrict__ bh,
    const float* __restrict__ wo, const float* __restrict__ so,
    unsigned char* __restrict__ ws)
{
    int i = blockIdx.x * 256 + threadIdx.x;
    if (i < 24576) {
        // hidden W frags, K-permutation baked in:
        // A[m][kslot(s,h,j)] = wh[l][feat][m]*sh[l][m], feat = 16s+8*(j>>2)+4h+(j&3)
        int j = i & 7, lane = (i >> 3) & 63, s = (i >> 9) & 3, t = (i >> 11) & 1, l = i >> 12;
        int m = 32 * t + (lane & 31);
        int h = lane >> 5;
        int feat = 16 * s + 8 * (j >> 2) + 4 * h + (j & 3);
        ((_Float16*)(ws + OFF_A))[i] = (_Float16)(wh[(l * 64 + feat) * 64 + m] * sh[l * 64 + m]);
    } else if (i < 24576 + 1024) {
        // layer-0 A frags; k=0..2 weights, k=3 carries bias (B supplies 1.0)
        int i2 = i - 24576;
        int j = i2 & 7, lane = (i2 >> 3) & 63, t = i2 >> 9;
        int m = 32 * t + (lane & 31);
        int k = 8 * (lane >> 5) + j;
        float v = (k < 3) ? w0[k * 64 + m] * s0[m] * 0.015625f
                          : (k == 3 ? b0[m] * 0.015625f : 0.f);
        ((_Float16*)(ws + OFF_B))[i2] = (_Float16)v;
    } else if (i < 24576 + 2048) {
        // biasAll frags: A[m][k=l] = bh[l][m]/64 (only h==0 k-slots 0..5)
        int i2 = i - 24576 - 1024;
        int j = i2 & 7, lane = (i2 >> 3) & 63, t = i2 >> 9;
        int m = 32 * t + (lane & 31);
        int h = lane >> 5;
        float v = (h == 0 && j < N_HID) ? bh[j * 64 + m] * 0.015625f : 0.f;
        ((_Float16*)(ws + OFF_E))[i2] = (_Float16)v;
    } else if (i < SETUP_TOTAL) {
        // wo*so*64 in C layout
        int i2 = i - 24576 - 2048;
        int r = i2 & 15, t = (i2 >> 4) & 1, h = i2 >> 5;
        int feat = 32 * t + (r & 3) + 8 * ((r >> 2) & 3) + 4 * h;
        ((float*)(ws + OFF_D))[i2] = wo[feat] * so[0] * 64.f;
    }
}

union FragU { int i[4]; half8 v; };

static __device__ __forceinline__ int pkrtz(float a, float b) {
    auto hh = __builtin_amdgcn_cvt_pkrtz(a, b);
    int r;
    __builtin_memcpy(&r, &hh, 4);
    return r;
}

// packed-fp16 leaky relu: max(u, 0.2*u) -> v_pk_mul_f16 + v_pk_max_f16
static __device__ __forceinline__ int lrelu2(int v) {
    half2v u;
    __builtin_memcpy(&u, &v, 4);
    half2v w = u * (_Float16)0.2f;
    half2v r = __builtin_elementwise_max(u, w);
    int o;
    __builtin_memcpy(&o, &r, 4);
    return o;
}

static __device__ __forceinline__ floatx16 mfma16(half8 a, half8 b, floatx16 c) {
    return __builtin_amdgcn_mfma_f32_32x32x16_f16(a, b, c, 0, 0, 0);
}

__global__ __launch_bounds__(64, 2) void mlp_mfma(
    const float* __restrict__ points,
    const unsigned char* __restrict__ ws,
    const float* __restrict__ bo,
    float* __restrict__ out, int n)
{
    const int lane = threadIdx.x;    // one wave per block
    const int p = lane & 31;
    const int h = lane >> 5;

    // ---- persistent register state (loaded once per wave) ----
    half8 Wreg[N_HID][2][4];
    {
        const half8* WfG = (const half8*)(ws + OFF_A);
#pragma unroll
        for (int l = 0; l < N_HID; ++l)
#pragma unroll
            for (int t = 0; t < 2; ++t)
#pragma unroll
                for (int s = 0; s < 4; ++s)
                    Wreg[l][t][s] = WfG[(((l * 2 + t) * 4 + s) << 6) + lane];
    }
    half8 W0a, W0b;
    {
        const half8* A0g = (const half8*)(ws + OFF_B);
        W0a = A0g[lane];
        W0b = A0g[64 + lane];
    }
    half8 biasAll0, biasAll1;
    {
        const half8* Eg = (const half8*)(ws + OFF_E);
        biasAll0 = Eg[lane];
        biasAll1 = Eg[64 + lane];
    }
    floatx16 wo0, wo1;
    {
        const floatx16* woG = (const floatx16*)(ws + OFF_D);
        wo0 = woG[h * 2 + 0];
        wo1 = woG[h * 2 + 1];
    }
    const float bov = bo[0];

    const int nbatch = (n + 63) >> 6;
    int b = blockIdx.x;
    if (b >= nbatch) return;

    // prime point prefetch
    float P0x, P0y, P0z, P1x, P1y, P1z;
    {
        int q0 = min(b * 64 + p, n - 1), q1 = min(b * 64 + 32 + p, n - 1);
        P0x = points[3 * q0]; P0y = points[3 * q0 + 1]; P0z = points[3 * q0 + 2];
        P1x = points[3 * q1]; P1y = points[3 * q1 + 1]; P1z = points[3 * q1 + 2];
    }

    while (true) {
        const int nb = b + (int)gridDim.x;
        const bool more = nb < nbatch;
        float N0x, N0y, N0z, N1x, N1y, N1z;
        N0x = N0y = N0z = N1x = N1y = N1z = 0.f;
        if (more) {
            int q0 = min(nb * 64 + p, n - 1), q1 = min(nb * 64 + 32 + p, n - 1);
            N0x = points[3 * q0]; N0y = points[3 * q0 + 1]; N0z = points[3 * q0 + 2];
            N1x = points[3 * q1]; N1y = points[3 * q1 + 1]; N1z = points[3 * q1 + 2];
        }

        // ---- layer 0 (bias via k=3 slot) ----
        floatx16 acc0[2], acc1[2];
        {
            FragU bu0, bu1;
            bu0.i[0] = bu0.i[1] = bu0.i[2] = bu0.i[3] = 0;
            bu1 = bu0;
            if (h == 0) {
                bu0.v[0] = (_Float16)P0x; bu0.v[1] = (_Float16)P0y;
                bu0.v[2] = (_Float16)P0z; bu0.v[3] = (_Float16)1.0f;
                bu1.v[0] = (_Float16)P1x; bu1.v[1] = (_Float16)P1y;
                bu1.v[2] = (_Float16)P1z; bu1.v[3] = (_Float16)1.0f;
            }
            acc0[0] = mfma16(W0a, bu0.v, (floatx16)(0.0f));
            acc0[1] = mfma16(W0b, bu0.v, (floatx16)(0.0f));
            acc1[0] = mfma16(W0a, bu1.v, (floatx16)(0.0f));
            acc1[1] = mfma16(W0b, bu1.v, (floatx16)(0.0f));
        }

        // ---- 6 hidden layers, JIT chunk pack + bias-broadcast MFMA ----
#pragma unroll
        for (int l = 0; l < N_HID; ++l) {
            // e_l: one-hot k=l B-frag (constant, hoisted by compiler)
            FragU e;
            e.i[0] = e.i[1] = e.i[2] = e.i[3] = 0;
            if (h == 0) e.i[l >> 1] = (l & 1) ? 0x3C000000 : 0x00003C00;
            floatx16 bc0 = mfma16(biasAll0, e.v, (floatx16)(0.0f));
            floatx16 bc1 = mfma16(biasAll1, e.v, (floatx16)(0.0f));
            floatx16 n00, n01, n10, n11;
#pragma unroll
            for (int s = 0; s < 4; ++s) {
                const int t = s >> 1, rpb = 4 * (s & 1);
                FragU f0, f1;
#pragma unroll
                for (int c = 0; c < 4; ++c) {
                    f0.i[c] = lrelu2(pkrtz(acc0[t][2 * (rpb + c)], acc0[t][2 * (rpb + c) + 1]));
                    f1.i[c] = lrelu2(pkrtz(acc1[t][2 * (rpb + c)], acc1[t][2 * (rpb + c) + 1]));
                }
                if (s == 0) {
                    n00 = mfma16(Wreg[l][0][0], f0.v, bc0);
                    n01 = mfma16(Wreg[l][1][0], f0.v, bc1);
                    n10 = mfma16(Wreg[l][0][0], f1.v, bc0);
                    n11 = mfma16(Wreg[l][1][0], f1.v, bc1);
                } else {
                    n00 = mfma16(Wreg[l][0][s], f0.v, n00);
                    n01 = mfma16(Wreg[l][1][s], f0.v, n01);
                    n10 = mfma16(Wreg[l][0][s], f1.v, n10);
                    n11 = mfma16(Wreg[l][1][s], f1.v, n11);
                }
            }
            acc0[0] = n00; acc0[1] = n01; acc1[0] = n10; acc1[1] = n11;
        }

        // ---- output: fp32 packed lrelu + dot with wo, cross-half reduce ----
        {
            float2v q0 = {0.f, 0.f}, q1 = {0.f, 0.f};
#pragma unroll
            for (int r2 = 0; r2 < 8; ++r2) {
                float2v w0p = { wo0[2 * r2], wo0[2 * r2 + 1] };
                float2v w1p = { wo1[2 * r2], wo1[2 * r2 + 1] };
                float2v u;
                u.x = acc0[0][2 * r2]; u.y = acc0[0][2 * r2 + 1];
                u = __builtin_elementwise_max(u, 0.2f * u);
                q0 += u * w0p;
                u.x = acc0[1][2 * r2]; u.y = acc0[1][2 * r2 + 1];
                u = __builtin_elementwise_max(u, 0.2f * u);
                q0 += u * w1p;
                u.x = acc1[0][2 * r2]; u.y = acc1[0][2 * r2 + 1];
                u = __builtin_elementwise_max(u, 0.2f * u);
                q1 += u * w0p;
                u.x = acc1[1][2 * r2]; u.y = acc1[1][2 * r2 + 1];
                u = __builtin_elementwise_max(u, 0.2f * u);
                q1 += u * w1p;
            }
            float part0 = q0.x + q0.y;
            float part1 = q1.x + q1.y;
            part0 += __shfl_xor(part0, 32);
            part1 += __shfl_xor(part1, 32);
            if (h == 0) {
                int pt0 = b * 64 + p, pt1 = b * 64 + 32 + p;
                if (pt0 < n) out[pt0] = part0 + bov;
                if (pt1 < n) out[pt1] = part1 + bov;
            }
        }

        if (!more) break;
        P0x = N0x; P0y = N0y; P0z = N0z;
        P1x = N1x; P1y = N1y; P1z = N1z;
        b = nb;
    }
}

extern "C" void kernel_launch(void* const* d_in, const int* in_sizes, int n_in,
                              void* d_out, int out_size, void* d_ws, size_t ws_size,
                              hipStream_t stream) {
    const float* points = (const float*)d_in[0];
    const float* w0     = (const float*)d_in[1];
    const float* s0     = (const float*)d_in[2];
    const float* b0     = (const float*)d_in[3];
    const float* wh     = (const float*)d_in[4];
    const float* sh     = (const float*)d_in[5];
    const float* bh     = (const float*)d_in[6];
    const float* wo     = (const float*)d_in[7];
    const float* so     = (const float*)d_in[8];
    const float* bo     = (const float*)d_in[9];

    const int n = in_sizes[0] / 3;

    setup_weights<<<(SETUP_TOTAL + 255) / 256, 256, 0, stream>>>(
        w0, s0, b0, wh, sh, bh, wo, so, (unsigned char*)d_ws);

    // 2048 persistent one-wave blocks -> 2 waves/SIMD; each does 8 batches.
    mlp_mfma<<<2048, 64, 0, stream>>>(
        points, (const unsigned char*)d_ws, bo, (float*)d_out, n);
}

// Round 7
// 134.093 us; speedup vs baseline: 1.4903x; 1.4903x over previous
//
#include <hip/hip_runtime.h>

// ImplicitFunction MLP via fp16 MFMA, round 7.
// R4 skeleton (W frags in LDS, 4-wave blocks) + R5/R6's register-bias tricks:
//  - layer-0 bias in W0's unused k=3 slot (B supplies 1.0)
//  - hidden biases: bc = mfma(biasAll, e_l, 0) broadcast from 8 persistent
//    VGPRs -> removes the 56 bias b128-equiv LDS reads/wave-batch that
//    dominated R4's LDS port time (33us -> 18us floor).
//  - JIT per-s chunk packing (minimal fr liveness) -> total regs ~165 ->
//    __launch_bounds__(256,3): 3 waves/SIMD (R4 was VGPR+AGPR-capped at 2).
// R6 lesson: full register residency + >=2 waves/SIMD spills catastrophically
// (FETCH 350MB). Weights stay in LDS; only bias/wo state lives in regs.
//
// Math: activations scaled 1/64 (lrelu positively homogeneous); K-permuted
// weights make the layer transition exchange-free; lrelu in packed fp16.
// Layouts (gfx950, 32x32x16):
//   A/B frag: lane (i=lane&31, h=lane>>5) holds k = 8h+j, j=0..7
//   C/D:      col n = lane&31, row m = (r&3) + 8*(r>>2) + 4h, r=0..15

typedef _Float16 half8 __attribute__((ext_vector_type(8)));
typedef _Float16 half2v __attribute__((ext_vector_type(2)));
typedef float floatx16 __attribute__((ext_vector_type(16)));
typedef float float2v __attribute__((ext_vector_type(2)));

#define N_HID 6
// ws byte offsets; [0, IMG_BYTES) is staged to LDS
#define OFF_A 0        // hidden W frags [l:6][t:2][s:4][lane:64][j:8] fp16 = 49152
#define OFF_B 49152    // layer0 A frags [t:2][lane:64][j:8] fp16 (bias@k=3) = 2048
#define OFF_D 51200    // wo*so*64 fp32, C-layout [h:2][t:2][r:16]          = 256
#define IMG_BYTES 53248  // padded to 13*256*16 for guard-free staging
#define OFF_E 53248    // biasAll frags [t:2][lane:64][j:8] fp16 (k-slot=l) = 2048 (ws only)
#define SETUP_TOTAL (24576 + 1024 + 64 + 1024)

__global__ __launch_bounds__(256) void setup_weights(
    const float* __restrict__ w0, const float* __restrict__ s0, const float* __restrict__ b0,
    const float* __restrict__ wh, const float* __restrict__ sh, const float* __restrict__ bh,
    const float* __restrict__ wo, const float* __restrict__ so,
    unsigned char* __restrict__ ws)
{
    int i = blockIdx.x * 256 + threadIdx.x;
    if (i < 24576) {
        // hidden W frags, K-permutation baked in:
        // A[m][kslot(s,h,j)] = wh[l][feat][m]*sh[l][m], feat = 16s+8*(j>>2)+4h+(j&3)
        int j = i & 7, lane = (i >> 3) & 63, s = (i >> 9) & 3, t = (i >> 11) & 1, l = i >> 12;
        int m = 32 * t + (lane & 31);
        int h = lane >> 5;
        int feat = 16 * s + 8 * (j >> 2) + 4 * h + (j & 3);
        ((_Float16*)(ws + OFF_A))[i] = (_Float16)(wh[(l * 64 + feat) * 64 + m] * sh[l * 64 + m]);
    } else if (i < 24576 + 1024) {
        // layer-0 A frags; k=0..2 weights, k=3 carries bias (B supplies 1.0)
        int i2 = i - 24576;
        int j = i2 & 7, lane = (i2 >> 3) & 63, t = i2 >> 9;
        int m = 32 * t + (lane & 31);
        int k = 8 * (lane >> 5) + j;
        float v = (k < 3) ? w0[k * 64 + m] * s0[m] * 0.015625f
                          : (k == 3 ? b0[m] * 0.015625f : 0.f);
        ((_Float16*)(ws + OFF_B))[i2] = (_Float16)v;
    } else if (i < 24576 + 1024 + 64) {
        // wo*so*64 in C layout
        int i2 = i - 24576 - 1024;
        int r = i2 & 15, t = (i2 >> 4) & 1, h = i2 >> 5;
        int feat = 32 * t + (r & 3) + 8 * ((r >> 2) & 3) + 4 * h;
        ((float*)(ws + OFF_D))[i2] = wo[feat] * so[0] * 64.f;
    } else if (i < SETUP_TOTAL) {
        // biasAll frags: A[m][k=l] = bh[l][m]/64 (h==0 k-slots 0..5 only)
        int i2 = i - 24576 - 1024 - 64;
        int j = i2 & 7, lane = (i2 >> 3) & 63, t = i2 >> 9;
        int m = 32 * t + (lane & 31);
        int h = lane >> 5;
        float v = (h == 0 && j < N_HID) ? bh[j * 64 + m] * 0.015625f : 0.f;
        ((_Float16*)(ws + OFF_E))[i2] = (_Float16)v;
    }
}

union FragU { int i[4]; half8 v; };

static __device__ __forceinline__ int pkrtz(float a, float b) {
    auto hh = __builtin_amdgcn_cvt_pkrtz(a, b);
    int r;
    __builtin_memcpy(&r, &hh, 4);
    return r;
}

// packed-fp16 leaky relu: max(u, 0.2*u) -> v_pk_mul_f16 + v_pk_max_f16
static __device__ __forceinline__ int lrelu2(int v) {
    half2v u;
    __builtin_memcpy(&u, &v, 4);
    half2v w = u * (_Float16)0.2f;
    half2v r = __builtin_elementwise_max(u, w);
    int o;
    __builtin_memcpy(&o, &r, 4);
    return o;
}

static __device__ __forceinline__ floatx16 mfma16(half8 a, half8 b, floatx16 c) {
    return __builtin_amdgcn_mfma_f32_32x32x16_f16(a, b, c, 0, 0, 0);
}

__global__ __launch_bounds__(256, 3) void mlp_mfma(
    const float* __restrict__ points,
    const unsigned char* __restrict__ ws,
    const float* __restrict__ bo,
    float* __restrict__ out, int n)
{
    __shared__ __align__(16) unsigned char lds[IMG_BYTES];

    const int lane = threadIdx.x & 63;
    const int wv = threadIdx.x >> 6;
    const int p = lane & 31;
    const int h = lane >> 5;
    const int base = (blockIdx.x * 4 + wv) * 64;
    const int pt0 = base + p, pt1 = base + 32 + p;
    const int pl0 = min(pt0, n - 1), pl1 = min(pt1, n - 1);

    // issue point + bias loads BEFORE staging so global latency overlaps it
    const float P0x = points[3 * pl0], P0y = points[3 * pl0 + 1], P0z = points[3 * pl0 + 2];
    const float P1x = points[3 * pl1], P1y = points[3 * pl1 + 1], P1z = points[3 * pl1 + 2];
    const half8* Eg = (const half8*)(ws + OFF_E);
    const half8 biasAll0 = Eg[lane];
    const half8 biasAll1 = Eg[64 + lane];
    const float bov = bo[0];

    // stage weight image to LDS (53248 B = 13 * 256 * 16)
    {
        const uint4* src = (const uint4*)ws;
        uint4* dst = (uint4*)lds;
#pragma unroll
        for (int i = 0; i < 13; ++i) {
            int idx = threadIdx.x + 256 * i;
            dst[idx] = src[idx];
        }
    }
    __syncthreads();

    const half8* Wf = (const half8*)(lds + OFF_A);        // [l][t][s][lane]
    const half8* A0 = (const half8*)(lds + OFF_B);        // [t][lane]
    const floatx16* woC = (const floatx16*)(lds + OFF_D); // [h*2+t]

    floatx16 acc0[2], acc1[2];   // [mtile] for ntile 0 / 1

    // ---- layer 0 (bias via k=3 slot) ----
    {
        FragU bu0, bu1;
        bu0.i[0] = bu0.i[1] = bu0.i[2] = bu0.i[3] = 0;
        bu1 = bu0;
        if (h == 0) {
            bu0.v[0] = (_Float16)P0x; bu0.v[1] = (_Float16)P0y;
            bu0.v[2] = (_Float16)P0z; bu0.v[3] = (_Float16)1.0f;
            bu1.v[0] = (_Float16)P1x; bu1.v[1] = (_Float16)P1y;
            bu1.v[2] = (_Float16)P1z; bu1.v[3] = (_Float16)1.0f;
        }
        half8 a0 = A0[lane], a1 = A0[64 + lane];
        acc0[0] = mfma16(a0, bu0.v, (floatx16)(0.0f));
        acc0[1] = mfma16(a1, bu0.v, (floatx16)(0.0f));
        acc1[0] = mfma16(a0, bu1.v, (floatx16)(0.0f));
        acc1[1] = mfma16(a1, bu1.v, (floatx16)(0.0f));
    }

    // ---- 6 hidden layers: bias-broadcast MFMA init + JIT chunk pack ----
#pragma unroll
    for (int l = 0; l < N_HID; ++l) {
        // e_l: one-hot k=l B-frag (constants, hoisted)
        FragU e;
        e.i[0] = e.i[1] = e.i[2] = e.i[3] = 0;
        if (h == 0) e.i[l >> 1] = (l & 1) ? 0x3C000000 : 0x00003C00;
        floatx16 bc0 = mfma16(biasAll0, e.v, (floatx16)(0.0f));
        floatx16 bc1 = mfma16(biasAll1, e.v, (floatx16)(0.0f));
        const half8* wl = Wf + l * 512 + lane;   // + t*256 + s*64
        floatx16 n00, n01, n10, n11;
#pragma unroll
        for (int s = 0; s < 4; ++s) {
            half8 wt0 = wl[s * 64];
            half8 wt1 = wl[256 + s * 64];
            const int t = s >> 1, rpb = 4 * (s & 1);
            FragU f0, f1;
#pragma unroll
            for (int c = 0; c < 4; ++c) {
                f0.i[c] = lrelu2(pkrtz(acc0[t][2 * (rpb + c)], acc0[t][2 * (rpb + c) + 1]));
                f1.i[c] = lrelu2(pkrtz(acc1[t][2 * (rpb + c)], acc1[t][2 * (rpb + c) + 1]));
            }
            if (s == 0) {
                n00 = mfma16(wt0, f0.v, bc0);
                n01 = mfma16(wt1, f0.v, bc1);
                n10 = mfma16(wt0, f1.v, bc0);
                n11 = mfma16(wt1, f1.v, bc1);
            } else {
                n00 = mfma16(wt0, f0.v, n00);
                n01 = mfma16(wt1, f0.v, n01);
                n10 = mfma16(wt0, f1.v, n10);
                n11 = mfma16(wt1, f1.v, n11);
            }
        }
        acc0[0] = n00; acc0[1] = n01; acc1[0] = n10; acc1[1] = n11;
    }

    // ---- output: fp32 packed lrelu + dot with wo (LDS broadcast), reduce ----
    {
        floatx16 wo0 = woC[h * 2 + 0];
        floatx16 wo1 = woC[h * 2 + 1];
        float2v q0 = {0.f, 0.f}, q1 = {0.f, 0.f};
#pragma unroll
        for (int r2 = 0; r2 < 8; ++r2) {
            float2v w0p = { wo0[2 * r2], wo0[2 * r2 + 1] };
            float2v w1p = { wo1[2 * r2], wo1[2 * r2 + 1] };
            float2v u;
            u.x = acc0[0][2 * r2]; u.y = acc0[0][2 * r2 + 1];
            u = __builtin_elementwise_max(u, 0.2f * u);
            q0 += u * w0p;
            u.x = acc0[1][2 * r2]; u.y = acc0[1][2 * r2 + 1];
            u = __builtin_elementwise_max(u, 0.2f * u);
            q0 += u * w1p;
            u.x = acc1[0][2 * r2]; u.y = acc1[0][2 * r2 + 1];
            u = __builtin_elementwise_max(u, 0.2f * u);
            q1 += u * w0p;
            u.x = acc1[1][2 * r2]; u.y = acc1[1][2 * r2 + 1];
            u = __builtin_elementwise_max(u, 0.2f * u);
            q1 += u * w1p;
        }
        float part0 = q0.x + q0.y;
        float part1 = q1.x + q1.y;
        part0 += __shfl_xor(part0, 32);
        part1 += __shfl_xor(part1, 32);
        if (h == 0) {
            if (pt0 < n) out[pt0] = part0 + bov;
            if (pt1 < n) out[pt1] = part1 + bov;
        }
    }
}

extern "C" void kernel_launch(void* const* d_in, const int* in_sizes, int n_in,
                              void* d_out, int out_size, void* d_ws, size_t ws_size,
                              hipStream_t stream) {
    const float* points = (const float*)d_in[0];
    const float* w0     = (const float*)d_in[1];
    const float* s0     = (const float*)d_in[2];
    const float* b0     = (const float*)d_in[3];
    const float* wh     = (const float*)d_in[4];
    const float* sh     = (const float*)d_in[5];
    const float* bh     = (const float*)d_in[6];
    const float* wo     = (const float*)d_in[7];
    const float* so     = (const float*)d_in[8];
    const float* bo     = (const float*)d_in[9];

    const int n = in_sizes[0] / 3;

    setup_weights<<<(SETUP_TOTAL + 255) / 256, 256, 0, stream>>>(
        w0, s0, b0, wh, sh, bh, wo, so, (unsigned char*)d_ws);

    const int grid = (n + 255) / 256;  // 256 points per block (4 waves x 64)
    mlp_mfma<<<grid, 256, 0, stream>>>(
        points, (const unsigned char*)d_ws, bo, (float*)d_out, n);
}

// Round 8
// 133.959 us; speedup vs baseline: 1.4918x; 1.0010x over previous
//
#include <hip/hip_runtime.h>

// ImplicitFunction MLP via fp16 MFMA, round 8: liveness-restructured for
// 3 waves/SIMD.
//
// R7 diagnosis: MFMA pipe floor is ~24us (112 mfma/wave x 32 SIMD-cyc x 16
// waves/SIMD); wall 60us because occupancy stuck at 2 waves/SIMD -> VALU/DS
// can't hide under MFMA. Cap suspects: unified VGPR+AGPR liveness (~210) and
// LDS 53248 granule rounding.
// Changes:
//  - mtile-phased layer body: pack BOTH ntile frags first (acc dies, frags
//    32 regs), then phase0 = {n00,n10} using only W[mtile0]+bc0, phase1 =
//    {n01,n11} with W[mtile1]+bc1. Peak live ~145 regs (was ~210). Same MFMA
//    and ds_read counts.
//  - LDS image = W frags only (exactly 49152 B); layer-0 frags / wo /
//    biasAll read from global ws once per wave (L2-resident broadcast).
//
// Math (unchanged): activations scaled 1/64; K-permuted weights make the
// layer transition exchange-free; layer-0 bias in W0's k=3 slot; hidden
// biases remat via bc = mfma(biasAll, e_l, 0); lrelu in packed fp16.
// Layouts (gfx950, 32x32x16):
//   A/B frag: lane (i=lane&31, h=lane>>5) holds k = 8h+j, j=0..7
//   C/D:      col n = lane&31, row m = (r&3) + 8*(r>>2) + 4h, r=0..15

typedef _Float16 half8 __attribute__((ext_vector_type(8)));
typedef _Float16 half2v __attribute__((ext_vector_type(2)));
typedef float floatx16 __attribute__((ext_vector_type(16)));
typedef float float2v __attribute__((ext_vector_type(2)));

#define N_HID 6
// ws byte offsets; [0, LDS_BYTES) staged to LDS, rest read from global
#define OFF_A 0        // hidden W frags [l:6][t:2][s:4][lane:64][j:8] fp16 = 49152
#define LDS_BYTES 49152
#define OFF_B 49152    // layer0 A frags [t:2][lane:64][j:8] fp16 (bias@k=3) = 2048
#define OFF_D 51200    // wo*so*64 fp32, C-layout [h:2][t:2][r:16]           = 256
#define OFF_E 51456    // biasAll frags [t:2][lane:64][j:8] fp16 (k-slot=l)  = 2048
#define SETUP_TOTAL (24576 + 1024 + 64 + 1024)

__global__ __launch_bounds__(256) void setup_weights(
    const float* __restrict__ w0, const float* __restrict__ s0, const float* __restrict__ b0,
    const float* __restrict__ wh, const float* __restrict__ sh, const float* __restrict__ bh,
    const float* __restrict__ wo, const float* __restrict__ so,
    unsigned char* __restrict__ ws)
{
    int i = blockIdx.x * 256 + threadIdx.x;
    if (i < 24576) {
        // hidden W frags, K-permutation baked in:
        // A[m][kslot(s,h,j)] = wh[l][feat][m]*sh[l][m], feat = 16s+8*(j>>2)+4h+(j&3)
        int j = i & 7, lane = (i >> 3) & 63, s = (i >> 9) & 3, t = (i >> 11) & 1, l = i >> 12;
        int m = 32 * t + (lane & 31);
        int h = lane >> 5;
        int feat = 16 * s + 8 * (j >> 2) + 4 * h + (j & 3);
        ((_Float16*)(ws + OFF_A))[i] = (_Float16)(wh[(l * 64 + feat) * 64 + m] * sh[l * 64 + m]);
    } else if (i < 24576 + 1024) {
        // layer-0 A frags; k=0..2 weights, k=3 carries bias (B supplies 1.0)
        int i2 = i - 24576;
        int j = i2 & 7, lane = (i2 >> 3) & 63, t = i2 >> 9;
        int m = 32 * t + (lane & 31);
        int k = 8 * (lane >> 5) + j;
        float v = (k < 3) ? w0[k * 64 + m] * s0[m] * 0.015625f
                          : (k == 3 ? b0[m] * 0.015625f : 0.f);
        ((_Float16*)(ws + OFF_B))[i2] = (_Float16)v;
    } else if (i < 24576 + 1024 + 64) {
        // wo*so*64 in C layout
        int i2 = i - 24576 - 1024;
        int r = i2 & 15, t = (i2 >> 4) & 1, h = i2 >> 5;
        int feat = 32 * t + (r & 3) + 8 * ((r >> 2) & 3) + 4 * h;
        ((float*)(ws + OFF_D))[i2] = wo[feat] * so[0] * 64.f;
    } else if (i < SETUP_TOTAL) {
        // biasAll frags: A[m][k=l] = bh[l][m]/64 (h==0 k-slots 0..5 only)
        int i2 = i - 24576 - 1024 - 64;
        int j = i2 & 7, lane = (i2 >> 3) & 63, t = i2 >> 9;
        int m = 32 * t + (lane & 31);
        int h = lane >> 5;
        float v = (h == 0 && j < N_HID) ? bh[j * 64 + m] * 0.015625f : 0.f;
        ((_Float16*)(ws + OFF_E))[i2] = (_Float16)v;
    }
}

union FragU { int i[4]; half8 v; };

static __device__ __forceinline__ int pkrtz(float a, float b) {
    auto hh = __builtin_amdgcn_cvt_pkrtz(a, b);
    int r;
    __builtin_memcpy(&r, &hh, 4);
    return r;
}

// packed-fp16 leaky relu: max(u, 0.2*u) -> v_pk_mul_f16 + v_pk_max_f16
static __device__ __forceinline__ int lrelu2(int v) {
    half2v u;
    __builtin_memcpy(&u, &v, 4);
    half2v w = u * (_Float16)0.2f;
    half2v r = __builtin_elementwise_max(u, w);
    int o;
    __builtin_memcpy(&o, &r, 4);
    return o;
}

static __device__ __forceinline__ floatx16 mfma16(half8 a, half8 b, floatx16 c) {
    return __builtin_amdgcn_mfma_f32_32x32x16_f16(a, b, c, 0, 0, 0);
}

__global__ __launch_bounds__(256, 3) void mlp_mfma(
    const float* __restrict__ points,
    const unsigned char* __restrict__ ws,
    const float* __restrict__ bo,
    float* __restrict__ out, int n)
{
    __shared__ __align__(16) unsigned char lds[LDS_BYTES];

    const int lane = threadIdx.x & 63;
    const int wv = threadIdx.x >> 6;
    const int p = lane & 31;
    const int h = lane >> 5;
    const int base = (blockIdx.x * 4 + wv) * 64;
    const int pt0 = base + p, pt1 = base + 32 + p;
    const int pl0 = min(pt0, n - 1), pl1 = min(pt1, n - 1);

    // global loads issued before staging so their latency overlaps it
    const float P0x = points[3 * pl0], P0y = points[3 * pl0 + 1], P0z = points[3 * pl0 + 2];
    const float P1x = points[3 * pl1], P1y = points[3 * pl1 + 1], P1z = points[3 * pl1 + 2];
    const half8* Eg = (const half8*)(ws + OFF_E);
    const half8 biasAll0 = Eg[lane];
    const half8 biasAll1 = Eg[64 + lane];
    const half8* A0g = (const half8*)(ws + OFF_B);
    const half8 W0a = A0g[lane];
    const half8 W0b = A0g[64 + lane];
    const float bov = bo[0];

    // stage W image to LDS (49152 B = 12 * 256 * 16)
    {
        const uint4* src = (const uint4*)ws;
        uint4* dst = (uint4*)lds;
#pragma unroll
        for (int i = 0; i < 12; ++i) {
            int idx = threadIdx.x + 256 * i;
            dst[idx] = src[idx];
        }
    }
    __syncthreads();

    const half8* Wf = (const half8*)(lds + OFF_A);   // [l][t][s][lane]

    floatx16 acc0[2], acc1[2];   // [mtile] for ntile 0 / 1

    // ---- layer 0 (bias via k=3 slot) ----
    {
        FragU bu0, bu1;
        bu0.i[0] = bu0.i[1] = bu0.i[2] = bu0.i[3] = 0;
        bu1 = bu0;
        if (h == 0) {
            bu0.v[0] = (_Float16)P0x; bu0.v[1] = (_Float16)P0y;
            bu0.v[2] = (_Float16)P0z; bu0.v[3] = (_Float16)1.0f;
            bu1.v[0] = (_Float16)P1x; bu1.v[1] = (_Float16)P1y;
            bu1.v[2] = (_Float16)P1z; bu1.v[3] = (_Float16)1.0f;
        }
        const floatx16 z = (floatx16)(0.0f);
        acc0[0] = mfma16(W0a, bu0.v, z);
        acc0[1] = mfma16(W0b, bu0.v, z);
        acc1[0] = mfma16(W0a, bu1.v, z);
        acc1[1] = mfma16(W0b, bu1.v, z);
    }

    // ---- 6 hidden layers: pack-first, then mtile-phased MFMA ----
#pragma unroll
    for (int l = 0; l < N_HID; ++l) {
        // pack both ntiles' B-frags (acc dies here -> frags are 32 regs)
        FragU f0[4], f1[4];
#pragma unroll
        for (int s = 0; s < 4; ++s) {
            const int t = s >> 1, rpb = 4 * (s & 1);
#pragma unroll
            for (int c = 0; c < 4; ++c) {
                f0[s].i[c] = lrelu2(pkrtz(acc0[t][2 * (rpb + c)], acc0[t][2 * (rpb + c) + 1]));
                f1[s].i[c] = lrelu2(pkrtz(acc1[t][2 * (rpb + c)], acc1[t][2 * (rpb + c) + 1]));
            }
        }
        // e_l: one-hot k=l B-frag (constants, hoisted)
        FragU e;
        e.i[0] = e.i[1] = e.i[2] = e.i[3] = 0;
        if (h == 0) e.i[l >> 1] = (l & 1) ? 0x3C000000 : 0x00003C00;
        const half8* wl = Wf + l * 512 + lane;   // + t*256 + s*64
        const floatx16 z = (floatx16)(0.0f);

        // phase 0: mtile 0 for both ntiles (only W[0][*] + bc0 live)
        floatx16 bc0 = mfma16(biasAll0, e.v, z);
        floatx16 n00, n10;
#pragma unroll
        for (int s = 0; s < 4; ++s) {
            half8 wt = wl[s * 64];
            n00 = mfma16(wt, f0[s].v, (s == 0) ? bc0 : n00);
            n10 = mfma16(wt, f1[s].v, (s == 0) ? bc0 : n10);
        }
        // phase 1: mtile 1
        floatx16 bc1 = mfma16(biasAll1, e.v, z);
        floatx16 n01, n11;
#pragma unroll
        for (int s = 0; s < 4; ++s) {
            half8 wt = wl[256 + s * 64];
            n01 = mfma16(wt, f0[s].v, (s == 0) ? bc1 : n01);
            n11 = mfma16(wt, f1[s].v, (s == 0) ? bc1 : n11);
        }
        acc0[0] = n00; acc0[1] = n01; acc1[0] = n10; acc1[1] = n11;
    }

    // ---- output: fp32 packed lrelu + dot with wo (global, C-layout) ----
    {
        const floatx16* woG = (const floatx16*)(ws + OFF_D);
        floatx16 wo0 = woG[h * 2 + 0];
        floatx16 wo1 = woG[h * 2 + 1];
        float2v q0 = {0.f, 0.f}, q1 = {0.f, 0.f};
#pragma unroll
        for (int r2 = 0; r2 < 8; ++r2) {
            float2v w0p = { wo0[2 * r2], wo0[2 * r2 + 1] };
            float2v w1p = { wo1[2 * r2], wo1[2 * r2 + 1] };
            float2v u;
            u.x = acc0[0][2 * r2]; u.y = acc0[0][2 * r2 + 1];
            u = __builtin_elementwise_max(u, 0.2f * u);
            q0 += u * w0p;
            u.x = acc0[1][2 * r2]; u.y = acc0[1][2 * r2 + 1];
            u = __builtin_elementwise_max(u, 0.2f * u);
            q0 += u * w1p;
            u.x = acc1[0][2 * r2]; u.y = acc1[0][2 * r2 + 1];
            u = __builtin_elementwise_max(u, 0.2f * u);
            q1 += u * w0p;
            u.x = acc1[1][2 * r2]; u.y = acc1[1][2 * r2 + 1];
            u = __builtin_elementwise_max(u, 0.2f * u);
            q1 += u * w1p;
        }
        float part0 = q0.x + q0.y;
        float part1 = q1.x + q1.y;
        part0 += __shfl_xor(part0, 32);
        part1 += __shfl_xor(part1, 32);
        if (h == 0) {
            if (pt0 < n) out[pt0] = part0 + bov;
            if (pt1 < n) out[pt1] = part1 + bov;
        }
    }
}

extern "C" void kernel_launch(void* const* d_in, const int* in_sizes, int n_in,
                              void* d_out, int out_size, void* d_ws, size_t ws_size,
                              hipStream_t stream) {
    const float* points = (const float*)d_in[0];
    const float* w0     = (const float*)d_in[1];
    const float* s0     = (const float*)d_in[2];
    const float* b0     = (const float*)d_in[3];
    const float* wh     = (const float*)d_in[4];
    const float* sh     = (const float*)d_in[5];
    const float* bh     = (const float*)d_in[6];
    const float* wo     = (const float*)d_in[7];
    const float* so     = (const float*)d_in[8];
    const float* bo     = (const float*)d_in[9];

    const int n = in_sizes[0] / 3;

    setup_weights<<<(SETUP_TOTAL + 255) / 256, 256, 0, stream>>>(
        w0, s0, b0, wh, sh, bh, wo, so, (unsigned char*)d_ws);

    const int grid = (n + 255) / 256;  // 256 points per block (4 waves x 64)
    mlp_mfma<<<grid, 256, 0, stream>>>(
        points, (const unsigned char*)d_ws, bo, (float*)d_out, n);
}